// Round 8
// baseline (302.350 us; speedup 1.0000x reference)
//
#include <hip/hip_runtime.h>
#include <stdint.h>

typedef __attribute__((ext_vector_type(8))) short s16x8;
typedef __attribute__((ext_vector_type(4))) float f32x4;

#define MFMA16(a, b, c) __builtin_amdgcn_mfma_f32_16x16x32_bf16((a), (b), (c), 0, 0, 0)

// ---------- helpers ----------
__device__ __forceinline__ unsigned short f2bf(float f) {
    unsigned int u = __float_as_uint(f);
    return (unsigned short)((u + 0x7FFFu + ((u >> 16) & 1u)) >> 16);
}
__device__ __forceinline__ float bf2f(unsigned short h) {
    return __uint_as_float(((unsigned int)h) << 16);
}
__device__ __forceinline__ void cvt8(unsigned short* dst, const float* src) {
    const float4 f0 = *(const float4*)(src);
    const float4 f1 = *(const float4*)(src + 4);
    s16x8 v;
    v[0] = (short)f2bf(f0.x); v[1] = (short)f2bf(f0.y);
    v[2] = (short)f2bf(f0.z); v[3] = (short)f2bf(f0.w);
    v[4] = (short)f2bf(f1.x); v[5] = (short)f2bf(f1.y);
    v[6] = (short)f2bf(f1.z); v[7] = (short)f2bf(f1.w);
    *(s16x8*)dst = v;
}
// async global->LDS DMA, 16 B/lane; LDS base wave-uniform, lane i -> base+i*16.
__device__ __forceinline__ void gl_lds16(const unsigned short* g, unsigned short* l) {
    __builtin_amdgcn_global_load_lds(
        (const __attribute__((address_space(1))) unsigned int*)g,
        (__attribute__((address_space(3))) unsigned int*)l,
        16, 0, 0);
}

// ---------- merged fp32 -> bf16 convert for x / Wqkv / Wfc (one launch) ----------
// Also zeroes the 32 LN panel-completion counters (block 0) each iteration,
// so the fused-LN gemm1 sees clean counters even after workspace re-poisoning.
__global__ __launch_bounds__(256) void cvt_all(const float* __restrict__ x,
                                               const float* __restrict__ wq,
                                               const float* __restrict__ wf,
                                               unsigned short* __restrict__ xb,
                                               unsigned short* __restrict__ wqb,
                                               unsigned short* __restrict__ wfb,
                                               unsigned int* __restrict__ cnt) {
    const int blk = blockIdx.x;  // 0..3135
    if (blk == 0 && threadIdx.x < 64) cnt[threadIdx.x] = 0;
    const float* src;
    unsigned short* dst;
    int base;
    if (blk < 2048)      { src = x;  dst = xb;  base = blk; }
    else if (blk < 2624) { src = wq; dst = wqb; base = blk - 2048; }
    else                 { src = wf; dst = wfb; base = blk - 2624; }
    const int i = (base * 256 + threadIdx.x) * 8;
    cvt8(&dst[i], &src[i]);
}

// ---------- GEMM r25: r23 structure (128x64, 48KB, XCD-pinned) + fused LN ----------
// lb(512,6) reverted (r7: +2.1us, suspected VGPR spill at the 85-reg cliff).
// DO_LN: after the C-stores, blocks of a bm panel count up via atomicAdd; the
// 18th (last) block LayerNorms the panel's 128 rows + writes the vT transpose.
// All 18 blocks of a bm share one XCD (bm>>2 == xcd under the pinned decode),
// so the panel is L2-local for the reader. Canonical last-block pattern:
// stores -> threadfence -> syncthreads -> atomicAdd; reader: observe count,
// threadfence (acquire), then read. Eliminates the ln_row launch; LN of early
// panels overlaps remaining gemm compute (only the last panel's LN ~2us exposed).
template <bool OUT_F32, bool DO_LN>
__global__ __launch_bounds__(512) void gemm_mn(const unsigned short* __restrict__ A,
                                               const unsigned short* __restrict__ Bw,
                                               void* __restrict__ Cout, int K, int N,
                                               const float* __restrict__ gamma,
                                               const float* __restrict__ beta,
                                               unsigned short* __restrict__ vT,
                                               unsigned int* __restrict__ cnt) {
    const int wg = blockIdx.x;
    const int xcd = wg & 7, j = wg >> 3;
    const int bm = (xcd << 2) + (j & 3);   // 4 A-panels per XCD (XCD = wg%8, m09/T1)
    const int bn = j >> 2;                 // all N-tiles per XCD
    const int t = threadIdx.x;
    const int lane = t & 63, w = t >> 6;          // 8 waves
    const int quad = lane >> 4, col = lane & 15;
    const int wm = (w >> 1) * 32, wn = (w & 1) * 32;  // wave = 32x32

    __shared__ alignas(16) unsigned short As[2][128 * 64];  // 2 x 16 KB, swizzled
    __shared__ alignas(16) unsigned short Bs[2][64 * 64];   // 2 x  8 KB, swizzled

    f32x4 acc[2][2];
#pragma unroll
    for (int i = 0; i < 2; ++i)
#pragma unroll
        for (int j2 = 0; j2 < 2; ++j2) acc[i][j2] = (f32x4){0.f, 0.f, 0.f, 0.f};

    const int lrow = lane >> 3;                      // 0..7
    const int lcol = ((lane & 7) ^ lrow) * 8;        // swizzled global chunk
    // wave w stages A rows [w*16, w*16+16) (2 issues) and B rows [w*8, w*8+8)
    const unsigned short* Ap = A + (size_t)(bm * 128 + w * 16 + lrow) * K + lcol;
    const unsigned short* Bp = Bw + (size_t)(bn * 64 + w * 8 + lrow) * K + lcol;

    // prime tile 0 into buffer 0
#pragma unroll
    for (int j2 = 0; j2 < 2; ++j2)
        gl_lds16(Ap + (size_t)(j2 * 8) * K, &As[0][(w * 16 + j2 * 8) * 64]);
    gl_lds16(Bp, &Bs[0][(w * 8) * 64]);
    __syncthreads();  // drain: tile 0 visible

    const int c7 = col & 7;
    const int fs0 = ((0 * 4 + quad) ^ c7) * 8;
    const int fs1 = ((1 * 4 + quad) ^ c7) * 8;

    for (int k0 = 0; k0 < K; k0 += 64) {
        const int p = (k0 >> 6) & 1;
        if (k0 + 64 < K) {  // stream next tile into the other buffer (no drain)
#pragma unroll
            for (int j2 = 0; j2 < 2; ++j2)
                gl_lds16(Ap + (size_t)(j2 * 8) * K + k0 + 64, &As[p ^ 1][(w * 16 + j2 * 8) * 64]);
            gl_lds16(Bp + k0 + 64, &Bs[p ^ 1][(w * 8) * 64]);
        }
        // hoist ALL 8 fragment loads, then run the 8 MFMAs
        s16x8 af[2][2], bfr[2][2];
#pragma unroll
        for (int s = 0; s < 2; ++s) {
            const int fs = s ? fs1 : fs0;
#pragma unroll
            for (int i = 0; i < 2; ++i)
                af[s][i] = *(const s16x8*)&As[p][(wm + i * 16 + col) * 64 + fs];
#pragma unroll
            for (int j2 = 0; j2 < 2; ++j2)
                bfr[s][j2] = *(const s16x8*)&Bs[p][(wn + j2 * 16 + col) * 64 + fs];
        }
#pragma unroll
        for (int s = 0; s < 2; ++s)
#pragma unroll
            for (int i = 0; i < 2; ++i)
#pragma unroll
                for (int j2 = 0; j2 < 2; ++j2)
                    acc[i][j2] = MFMA16(af[s][i], bfr[s][j2], acc[i][j2]);
        __syncthreads();
    }
    const int rowb = bm * 128 + wm + quad * 4;
    const int colb = bn * 64 + wn + col;
#pragma unroll
    for (int i = 0; i < 2; ++i)
#pragma unroll
        for (int j2 = 0; j2 < 2; ++j2)
#pragma unroll
            for (int r = 0; r < 4; ++r) {
                size_t off = (size_t)(rowb + i * 16 + r) * N + colb + j2 * 16;
                if (OUT_F32) ((float*)Cout)[off] = acc[i][j2][r];
                else ((unsigned short*)Cout)[off] = f2bf(acc[i][j2][r]);
            }

    if constexpr (DO_LN) {
        __shared__ int ticket_s;
        __threadfence();          // release: this thread's C-stores device-visible
        __syncthreads();          // all threads' store+fence done before the atomic
        if (t == 0) ticket_s = (int)atomicAdd(cnt + bm, 1u);
        __syncthreads();
        if (ticket_s == (N >> 6) - 1) {  // last of the panel's 18 blocks
            __threadfence();      // acquire: other blocks' stores visible
            unsigned short* qk = (unsigned short*)Cout;
            const int wv = t >> 6, ln2 = t & 63;
#pragma unroll 1
            for (int ri = 0; ri < 16; ++ri) {
                const int row = bm * 128 + wv * 16 + ri;
                const int bb = row >> 11, ll = row & 2047;
                unsigned short* rp = qk + (size_t)row * 1152;
                s16x8 v0 = *(const s16x8*)&rp[ln2 * 8];
                s16x8 v1 = *(const s16x8*)&rp[512 + ln2 * 8];
                unsigned int v2u = *(const unsigned int*)&rp[1024 + ln2 * 2];
                float f0[8], f1[8], f2[2];
                float s = 0.f, s2 = 0.f;
#pragma unroll
                for (int e = 0; e < 8; ++e) {
                    f0[e] = bf2f((unsigned short)v0[e]);
                    f1[e] = bf2f((unsigned short)v1[e]);
                    s += f0[e] + f1[e];
                    s2 += f0[e] * f0[e] + f1[e] * f1[e];
                }
                f2[0] = bf2f((unsigned short)(v2u & 0xFFFF));
                f2[1] = bf2f((unsigned short)(v2u >> 16));
                s += f2[0] + f2[1];
                s2 += f2[0] * f2[0] + f2[1] * f2[1];
#pragma unroll
                for (int off = 1; off < 64; off <<= 1) {
                    s += __shfl_xor(s, off);
                    s2 += __shfl_xor(s2, off);
                }
                const float mu = s * (1.0f / 1152.0f);
                float var = s2 * (1.0f / 1152.0f) - mu * mu;
                var = fmaxf(var, 0.0f);
                const float rstd = rsqrtf(var + 1e-5f);
                {
                    s16x8 o;
#pragma unroll
                    for (int e = 0; e < 8; ++e)
                        o[e] = (short)f2bf((f0[e] - mu) * rstd * gamma[ln2 * 8 + e] + beta[ln2 * 8 + e]);
                    *(s16x8*)&rp[ln2 * 8] = o;
                    if (ln2 >= 8 && ln2 < 16) {  // v head (cols 64..127) -> transposed copy
                        const int d0 = ln2 * 8 - 64;
#pragma unroll
                        for (int e = 0; e < 8; ++e)
                            vT[((size_t)(bb * 64 + d0 + e)) * 2048 + ll] = (unsigned short)o[e];
                    }
                }
                {
                    s16x8 o;
#pragma unroll
                    for (int e = 0; e < 8; ++e)
                        o[e] = (short)f2bf((f1[e] - mu) * rstd * gamma[512 + ln2 * 8 + e] + beta[512 + ln2 * 8 + e]);
                    *(s16x8*)&rp[512 + ln2 * 8] = o;
                }
                {
                    unsigned short o0 = f2bf((f2[0] - mu) * rstd * gamma[1024 + ln2 * 2] + beta[1024 + ln2 * 2]);
                    unsigned short o1 = f2bf((f2[1] - mu) * rstd * gamma[1025 + ln2 * 2] + beta[1025 + ln2 * 2]);
                    *(unsigned int*)&rp[1024 + ln2 * 2] = ((unsigned int)o1 << 16) | o0;
                }
            }
        }
    }
}

// ---------- Flash-style causal MQA — r24 version (l via VALU psum) ----------
__global__ __launch_bounds__(512, 4) void attn_kernel(const unsigned short* __restrict__ qkvn,
                                                      const unsigned short* __restrict__ vT,
                                                      unsigned short* __restrict__ obuf) {
    const int b = blockIdx.x >> 3, hp = blockIdx.x & 7;
    const int yy = blockIdx.y;
    const int qb = (yy < 16) ? (31 - yy) : (yy - 16);  // CU-paired: (31-a)+a = 33 iters/CU
    const int t = threadIdx.x;
    const int lane = t & 63, w = t >> 6;
    const int quad = lane >> 4, col = lane & 15;
    const int hl = w >> 2;              // head-local 0/1
    const int qhalf = (w >> 1) & 1;     // 32-q group within head
    const int kpar = w & 1;             // k-half of the 64-k tile

    __shared__ alignas(16) unsigned char SM[53248];
    unsigned short* Ks0 = (unsigned short*)SM;             // 8192 shorts
    unsigned short* Vt0 = (unsigned short*)(SM + 16384);   // 8192 shorts
    unsigned short* Qs  = (unsigned short*)(SM + 32768);   // [128][80] prologue view
    unsigned short* Ps  = (unsigned short*)(SM + 32768) + w * 1280;  // per-wave [32][40]

    const int srow = t >> 3;                  // 0..63
    const int schunk = t & 7;                 // global 8-short chunk
    const int ldsoff = srow * 64 + (schunk ^ (srow & 7)) * 8;  // swizzled LDS addr (shorts)

    // stage Q for both heads, pre-scaled by 1/8 (exact in bf16); stride 80 shorts
#pragma unroll
    for (int hh = 0; hh < 2; ++hh) {
        const unsigned short* qsrc =
            qkvn + (size_t)(b * 2048 + qb * 64 + srow) * 1152 + 128 + (hp * 2 + hh) * 64 + schunk * 8;
        s16x8 v = *(const s16x8*)qsrc;
#pragma unroll
        for (int e = 0; e < 8; ++e)
            v[e] = (short)f2bf(bf2f((unsigned short)v[e]) * 0.125f);
        *(s16x8*)&Qs[(hh * 64 + srow) * 80 + schunk * 8] = v;
    }
    __syncthreads();
    s16x8 qfr[2][2];
#pragma unroll
    for (int qf = 0; qf < 2; ++qf)
#pragma unroll
        for (int dh = 0; dh < 2; ++dh)
            qfr[qf][dh] = *(const s16x8*)&Qs[(hl * 64 + qhalf * 32 + qf * 16 + col) * 80 + dh * 32 + quad * 8];

    // stage K/V tile 0 (global reads linear; LDS writes swizzled)
    const unsigned short* kbase = qkvn + (size_t)(b * 2048 + srow) * 1152 + schunk * 8;  // + kb*64*1152
    const unsigned short* vbase = vT + (size_t)(b * 64 + srow) * 2048 + schunk * 8;      // + kb*64
    *(uint4*)&Ks0[ldsoff] = *(const uint4*)(kbase);
    *(uint4*)&Vt0[ldsoff] = *(const uint4*)(vbase);
    __syncthreads();  // KV0 visible; all Q-frag reads done -> PQ reusable as P

    const int c7 = col & 7;
    const int koff0 = (kpar * 32 + col) * 128 + ((quad ^ c7) * 16);
    const int koff1 = (kpar * 32 + col) * 128 + (((4 + quad) ^ c7) * 16);
    const int voff = col * 128 + (((kpar * 4 + quad) ^ c7) * 16);

    f32x4 Oacc[4][2];     // [d-subtile][q-frag] of O^T[d][q]
    float psum[2] = {0.f, 0.f};  // [q-frag] partial l (this lane's k-share)
#pragma unroll
    for (int ds = 0; ds < 4; ++ds)
#pragma unroll
        for (int qf = 0; qf < 2; ++qf) Oacc[ds][qf] = (f32x4){0.f, 0.f, 0.f, 0.f};

    const int qbase = qb * 64 + qhalf * 32;   // + qf*16 + col = this lane's q rows

    for (int kb = 0; kb <= qb; ++kb) {
        const int p = kb & 1;
        uint4 kreg, vreg;
        if (kb < qb) {  // issue next tile's global loads before compute
            kreg = *(const uint4*)(kbase + (size_t)(kb + 1) * 64 * 1152);
            vreg = *(const uint4*)(vbase + (kb + 1) * 64);
        }
        const bool diag = (kb == qb);
        if (!(diag && kpar == 1 && qhalf == 0)) {
            const bool needmask = diag && (kpar == qhalf);
            const char* kb8 = (const char*)(Ks0 + p * 4096);
            const char* vb8 = (const char*)(Vt0 + p * 4096);

#pragma unroll
            for (int nt = 0; nt < 2; ++nt) {
                const s16x8 kf0 = *(const s16x8*)(kb8 + nt * 2048 + koff0);
                const s16x8 kf1 = *(const s16x8*)(kb8 + nt * 2048 + koff1);
#pragma unroll
                for (int qf = 0; qf < 2; ++qf) {
                    f32x4 z = (f32x4){-12.f, -12.f, -12.f, -12.f};  // exp bias via C-in
                    z = MFMA16(kf0, qfr[qf][0], z);   // A=K, B=Q -> S^T[k][q] - 12
                    z = MFMA16(kf1, qfr[qf][1], z);
                    const int qg = qbase + qf * 16 + col;
                    const int kl = kb * 64 + kpar * 32 + nt * 16 + quad * 4;
                    float ev[4];
#pragma unroll
                    for (int r = 0; r < 4; ++r) {
                        float sv = z[r];
                        if (needmask && (kl + r > qg)) sv = -1e30f;
                        ev[r] = __expf(sv);
                    }
                    psum[qf] += (ev[0] + ev[1]) + (ev[2] + ev[3]);  // l partial in VALU
                    unsigned int plo, phi;
                    asm("v_cvt_pk_bf16_f32 %0, %1, %2" : "=v"(plo) : "v"(ev[0]), "v"(ev[1]));
                    asm("v_cvt_pk_bf16_f32 %0, %1, %2" : "=v"(phi) : "v"(ev[2]), "v"(ev[3]));
                    uint2 pk2;
                    pk2.x = plo; pk2.y = phi;
                    *(uint2*)&Ps[(qf * 16 + col) * 40 + nt * 16 + quad * 4] = pk2;  // 8B, k-contig
                }
            }

            const s16x8 pf0 = *(const s16x8*)&Ps[col * 40 + quad * 8];          // B: P[q][k]
            const s16x8 pf1 = *(const s16x8*)&Ps[(16 + col) * 40 + quad * 8];
            __builtin_amdgcn_s_setprio(1);
#pragma unroll
            for (int ds = 0; ds < 4; ++ds) {
                const s16x8 vf = *(const s16x8*)(vb8 + ds * 2048 + voff);
                Oacc[ds][0] = MFMA16(vf, pf0, Oacc[ds][0]);   // A=V^T, B=P^T -> O^T[d][q]
                Oacc[ds][1] = MFMA16(vf, pf1, Oacc[ds][1]);
            }
            __builtin_amdgcn_s_setprio(0);
        }

        if (kb < qb) {  // LDS-write prefetched tile into the other (swizzled) buffer
            *(uint4*)&Ks0[(p ^ 1) * 4096 + ldsoff] = kreg;
            *(uint4*)&Vt0[(p ^ 1) * 4096 + ldsoff] = vreg;
        }
        __syncthreads();  // ONE barrier per iter
    }

    // finish l: each lane's psum covers its quad's k-rows; reduce across quads
#pragma unroll
    for (int qf = 0; qf < 2; ++qf) {
        psum[qf] += __shfl_xor(psum[qf], 16);
        psum[qf] += __shfl_xor(psum[qf], 32);
    }

    // ---- epilogue: merge k-split partials of wave pair (w, w^1) through LDS ----
    float* mg = (float*)SM + (hl * 2 + qhalf) * 2112;
    float* lm = (float*)(SM + 33792) + (hl * 2 + qhalf) * 32;
    if (kpar) {
#pragma unroll
        for (int ds = 0; ds < 4; ++ds)
#pragma unroll
            for (int qf = 0; qf < 2; ++qf)
#pragma unroll
                for (int r = 0; r < 4; ++r)
                    mg[(ds * 16 + quad * 4 + r) * 33 + qf * 16 + col] = Oacc[ds][qf][r];
        if (quad == 0) { lm[col] = psum[0]; lm[16 + col] = psum[1]; }
    }
    __syncthreads();
    if (!kpar) {
        const int h = hp * 2 + hl;
#pragma unroll
        for (int qf = 0; qf < 2; ++qf) {
            const int qglob = qbase + qf * 16 + col;
            const float inv = 1.0f / (psum[qf] + lm[qf * 16 + col]);
            const size_t base = (((size_t)b * 2048 + qglob) * 16 + h) * 64 + quad * 4;
#pragma unroll
            for (int ds = 0; ds < 4; ++ds) {
                ushort4 ov;
                unsigned short* op = (unsigned short*)&ov;
#pragma unroll
                for (int r = 0; r < 4; ++r)
                    op[r] = f2bf((Oacc[ds][qf][r] + mg[(ds * 16 + quad * 4 + r) * 33 + qf * 16 + col]) * inv);
                *(ushort4*)&obuf[base + ds * 16] = ov;  // 8B packed store, d-contig
            }
        }
    }
}

// ---------- launch ----------
extern "C" void kernel_launch(void* const* d_in, const int* in_sizes, int n_in,
                              void* d_out, int out_size, void* d_ws, size_t ws_size,
                              hipStream_t stream) {
    (void)in_sizes; (void)n_in; (void)out_size; (void)ws_size;
    const float* x     = (const float*)d_in[0];  // (2,2048,1024) fp32
    const float* Wqkv  = (const float*)d_in[1];  // (1152,1024)  fp32
    const float* gamma = (const float*)d_in[2];  // (1152,)      fp32
    const float* beta  = (const float*)d_in[3];  // (1152,)      fp32
    const float* Wfc   = (const float*)d_in[4];  // (1024,1024)  fp32
    float* out = (float*)d_out;                  // (2,2048,1024) fp32

    // ws: fill poisons ~268 MB each iter -> workspace is >=256 MiB; counters at 22 MiB.
    char* ws = (char*)d_ws;
    unsigned short* xb   = (unsigned short*)ws;               // 8,388,608
    unsigned short* Wqb  = (unsigned short*)(ws + 8388608);   // 2,359,296
    unsigned short* Wfb  = (unsigned short*)(ws + 10747904);  // 2,097,152
    unsigned short* qkvn = (unsigned short*)(ws + 12845056);  // 9,437,184
    unsigned short* vT   = (unsigned short*)(ws + 22282240);  //   524,288
    unsigned int*   cnt  = (unsigned int*)(ws + 23068672);    //       256 (LN counters)
    unsigned short* abuf = (unsigned short*)ws;               // alias xb (dead after gemm1)

    cvt_all<<<dim3(3136), 256, 0, stream>>>(x, Wqkv, Wfc, xb, Wqb, Wfb, cnt);
    gemm_mn<false, true><<<dim3(576), 512, 0, stream>>>(xb, Wqb, qkvn, 1024, 1152,
                                                        gamma, beta, vT, cnt);
    attn_kernel<<<dim3(16, 32), 512, 0, stream>>>(qkvn, vT, abuf);
    gemm_mn<true, false><<<dim3(512), 512, 0, stream>>>(abuf, Wfb, out, 1024, 1024,
                                                        nullptr, nullptr, nullptr, nullptr);
}

// Round 9
// 145.711 us; speedup vs baseline: 2.0750x; 2.0750x over previous
//
#include <hip/hip_runtime.h>
#include <stdint.h>

typedef __attribute__((ext_vector_type(8))) short s16x8;
typedef __attribute__((ext_vector_type(4))) float f32x4;

#define MFMA16(a, b, c) __builtin_amdgcn_mfma_f32_16x16x32_bf16((a), (b), (c), 0, 0, 0)

// ---------- helpers ----------
__device__ __forceinline__ unsigned short f2bf(float f) {
    unsigned int u = __float_as_uint(f);
    return (unsigned short)((u + 0x7FFFu + ((u >> 16) & 1u)) >> 16);
}
__device__ __forceinline__ float bf2f(unsigned short h) {
    return __uint_as_float(((unsigned int)h) << 16);
}
__device__ __forceinline__ void cvt8(unsigned short* dst, const float* src) {
    const float4 f0 = *(const float4*)(src);
    const float4 f1 = *(const float4*)(src + 4);
    s16x8 v;
    v[0] = (short)f2bf(f0.x); v[1] = (short)f2bf(f0.y);
    v[2] = (short)f2bf(f0.z); v[3] = (short)f2bf(f0.w);
    v[4] = (short)f2bf(f1.x); v[5] = (short)f2bf(f1.y);
    v[6] = (short)f2bf(f1.z); v[7] = (short)f2bf(f1.w);
    *(s16x8*)dst = v;
}
// async global->LDS DMA, 16 B/lane; LDS base wave-uniform, lane i -> base+i*16.
__device__ __forceinline__ void gl_lds16(const unsigned short* g, unsigned short* l) {
    __builtin_amdgcn_global_load_lds(
        (const __attribute__((address_space(1))) unsigned int*)g,
        (__attribute__((address_space(3))) unsigned int*)l,
        16, 0, 0);
}

// ---------- merged fp32 -> bf16 convert for x / Wqkv / Wfc (one launch) ----------
__global__ __launch_bounds__(256) void cvt_all(const float* __restrict__ x,
                                               const float* __restrict__ wq,
                                               const float* __restrict__ wf,
                                               unsigned short* __restrict__ xb,
                                               unsigned short* __restrict__ wqb,
                                               unsigned short* __restrict__ wfb) {
    const int blk = blockIdx.x;  // 0..3135
    const float* src;
    unsigned short* dst;
    int base;
    if (blk < 2048)      { src = x;  dst = xb;  base = blk; }
    else if (blk < 2624) { src = wq; dst = wqb; base = blk - 2048; }
    else                 { src = wf; dst = wfb; base = blk - 2624; }
    const int i = (base * 256 + threadIdx.x) * 8;
    cvt8(&dst[i], &src[i]);
}

// ---------- GEMM r26 == r23/r6 (best-known): 128x64, 48KB dbuf, XCD-pinned ----------
// r8 POST-MORTEM: fused-LN's __threadfence() per block = L2 writeback on
// non-coherent-L2 hardware -> 576 serialized flushes, gemm1 191us. Kernel
// boundaries are the cheap fence on this chip; keep LN as its own launch.
// r7's lb(512,6) also reverted (VGPR-spill regression, +2.1us).
template <bool OUT_F32>
__global__ __launch_bounds__(512) void gemm_mn(const unsigned short* __restrict__ A,
                                               const unsigned short* __restrict__ Bw,
                                               void* __restrict__ Cout, int K, int N) {
    const int wg = blockIdx.x;
    const int xcd = wg & 7, j = wg >> 3;
    const int bm = (xcd << 2) + (j & 3);   // 4 A-panels per XCD (XCD = wg%8, m09/T1)
    const int bn = j >> 2;                 // all N-tiles per XCD
    const int t = threadIdx.x;
    const int lane = t & 63, w = t >> 6;          // 8 waves
    const int quad = lane >> 4, col = lane & 15;
    const int wm = (w >> 1) * 32, wn = (w & 1) * 32;  // wave = 32x32

    __shared__ alignas(16) unsigned short As[2][128 * 64];  // 2 x 16 KB, swizzled
    __shared__ alignas(16) unsigned short Bs[2][64 * 64];   // 2 x  8 KB, swizzled

    f32x4 acc[2][2];
#pragma unroll
    for (int i = 0; i < 2; ++i)
#pragma unroll
        for (int j2 = 0; j2 < 2; ++j2) acc[i][j2] = (f32x4){0.f, 0.f, 0.f, 0.f};

    const int lrow = lane >> 3;                      // 0..7
    const int lcol = ((lane & 7) ^ lrow) * 8;        // swizzled global chunk
    // wave w stages A rows [w*16, w*16+16) (2 issues) and B rows [w*8, w*8+8)
    const unsigned short* Ap = A + (size_t)(bm * 128 + w * 16 + lrow) * K + lcol;
    const unsigned short* Bp = Bw + (size_t)(bn * 64 + w * 8 + lrow) * K + lcol;

    // prime tile 0 into buffer 0
#pragma unroll
    for (int j2 = 0; j2 < 2; ++j2)
        gl_lds16(Ap + (size_t)(j2 * 8) * K, &As[0][(w * 16 + j2 * 8) * 64]);
    gl_lds16(Bp, &Bs[0][(w * 8) * 64]);
    __syncthreads();  // drain: tile 0 visible

    const int c7 = col & 7;
    const int fs0 = ((0 * 4 + quad) ^ c7) * 8;
    const int fs1 = ((1 * 4 + quad) ^ c7) * 8;

    for (int k0 = 0; k0 < K; k0 += 64) {
        const int p = (k0 >> 6) & 1;
        if (k0 + 64 < K) {  // stream next tile into the other buffer (no drain)
#pragma unroll
            for (int j2 = 0; j2 < 2; ++j2)
                gl_lds16(Ap + (size_t)(j2 * 8) * K + k0 + 64, &As[p ^ 1][(w * 16 + j2 * 8) * 64]);
            gl_lds16(Bp + k0 + 64, &Bs[p ^ 1][(w * 8) * 64]);
        }
        // hoist ALL 8 fragment loads, then run the 8 MFMAs
        s16x8 af[2][2], bfr[2][2];
#pragma unroll
        for (int s = 0; s < 2; ++s) {
            const int fs = s ? fs1 : fs0;
#pragma unroll
            for (int i = 0; i < 2; ++i)
                af[s][i] = *(const s16x8*)&As[p][(wm + i * 16 + col) * 64 + fs];
#pragma unroll
            for (int j2 = 0; j2 < 2; ++j2)
                bfr[s][j2] = *(const s16x8*)&Bs[p][(wn + j2 * 16 + col) * 64 + fs];
        }
#pragma unroll
        for (int s = 0; s < 2; ++s)
#pragma unroll
            for (int i = 0; i < 2; ++i)
#pragma unroll
                for (int j2 = 0; j2 < 2; ++j2)
                    acc[i][j2] = MFMA16(af[s][i], bfr[s][j2], acc[i][j2]);
        __syncthreads();
    }
    const int rowb = bm * 128 + wm + quad * 4;
    const int colb = bn * 64 + wn + col;
#pragma unroll
    for (int i = 0; i < 2; ++i)
#pragma unroll
        for (int j2 = 0; j2 < 2; ++j2)
#pragma unroll
            for (int r = 0; r < 4; ++r) {
                size_t off = (size_t)(rowb + i * 16 + r) * N + colb + j2 * 16;
                if (OUT_F32) ((float*)Cout)[off] = acc[i][j2][r];
                else ((unsigned short*)Cout)[off] = f2bf(acc[i][j2][r]);
            }
}

// ---------- LayerNorm over 1152, one WAVE per row (r6 version) ----------
__global__ __launch_bounds__(64) void ln_row(unsigned short* __restrict__ qkvn,
                                             const float* __restrict__ gamma,
                                             const float* __restrict__ beta,
                                             unsigned short* __restrict__ vT) {
    const int row = blockIdx.x;  // b*2048 + l
    const int b = row >> 11, l = row & 2047;
    unsigned short* rp = qkvn + (size_t)row * 1152;
    const int lane = threadIdx.x;

    s16x8 v0 = *(const s16x8*)&rp[lane * 8];
    s16x8 v1 = *(const s16x8*)&rp[512 + lane * 8];
    unsigned int v2u = *(const unsigned int*)&rp[1024 + lane * 2];

    float f0[8], f1[8], f2[2];
    float s = 0.f, s2 = 0.f;
#pragma unroll
    for (int e = 0; e < 8; ++e) {
        f0[e] = bf2f((unsigned short)v0[e]);
        f1[e] = bf2f((unsigned short)v1[e]);
        s += f0[e] + f1[e];
        s2 += f0[e] * f0[e] + f1[e] * f1[e];
    }
    f2[0] = bf2f((unsigned short)(v2u & 0xFFFF));
    f2[1] = bf2f((unsigned short)(v2u >> 16));
    s += f2[0] + f2[1];
    s2 += f2[0] * f2[0] + f2[1] * f2[1];

#pragma unroll
    for (int off = 1; off < 64; off <<= 1) {
        s += __shfl_xor(s, off);
        s2 += __shfl_xor(s2, off);
    }
    const float mu = s * (1.0f / 1152.0f);
    float var = s2 * (1.0f / 1152.0f) - mu * mu;
    var = fmaxf(var, 0.0f);
    const float rstd = rsqrtf(var + 1e-5f);

    {
        s16x8 o;
#pragma unroll
        for (int e = 0; e < 8; ++e)
            o[e] = (short)f2bf((f0[e] - mu) * rstd * gamma[lane * 8 + e] + beta[lane * 8 + e]);
        *(s16x8*)&rp[lane * 8] = o;
        if (lane >= 8 && lane < 16) {  // v head (cols 64..127) -> transposed copy
            const int d0 = lane * 8 - 64;
#pragma unroll
            for (int e = 0; e < 8; ++e)
                vT[((size_t)(b * 64 + d0 + e)) * 2048 + l] = (unsigned short)o[e];
        }
    }
    {
        s16x8 o;
#pragma unroll
        for (int e = 0; e < 8; ++e)
            o[e] = (short)f2bf((f1[e] - mu) * rstd * gamma[512 + lane * 8 + e] + beta[512 + lane * 8 + e]);
        *(s16x8*)&rp[512 + lane * 8] = o;
    }
    {
        unsigned short o0 = f2bf((f2[0] - mu) * rstd * gamma[1024 + lane * 2] + beta[1024 + lane * 2]);
        unsigned short o1 = f2bf((f2[1] - mu) * rstd * gamma[1025 + lane * 2] + beta[1025 + lane * 2]);
        *(unsigned int*)&rp[1024 + lane * 2] = ((unsigned int)o1 << 16) | o0;
    }
}

// ---------- Flash-style causal MQA — r24 attn (l via VALU psum), unchanged ----------
__global__ __launch_bounds__(512, 4) void attn_kernel(const unsigned short* __restrict__ qkvn,
                                                      const unsigned short* __restrict__ vT,
                                                      unsigned short* __restrict__ obuf) {
    const int b = blockIdx.x >> 3, hp = blockIdx.x & 7;
    const int yy = blockIdx.y;
    const int qb = (yy < 16) ? (31 - yy) : (yy - 16);  // CU-paired: (31-a)+a = 33 iters/CU
    const int t = threadIdx.x;
    const int lane = t & 63, w = t >> 6;
    const int quad = lane >> 4, col = lane & 15;
    const int hl = w >> 2;              // head-local 0/1
    const int qhalf = (w >> 1) & 1;     // 32-q group within head
    const int kpar = w & 1;             // k-half of the 64-k tile

    __shared__ alignas(16) unsigned char SM[53248];
    unsigned short* Ks0 = (unsigned short*)SM;             // 8192 shorts
    unsigned short* Vt0 = (unsigned short*)(SM + 16384);   // 8192 shorts
    unsigned short* Qs  = (unsigned short*)(SM + 32768);   // [128][80] prologue view
    unsigned short* Ps  = (unsigned short*)(SM + 32768) + w * 1280;  // per-wave [32][40]

    const int srow = t >> 3;                  // 0..63
    const int schunk = t & 7;                 // global 8-short chunk
    const int ldsoff = srow * 64 + (schunk ^ (srow & 7)) * 8;  // swizzled LDS addr (shorts)

    // stage Q for both heads, pre-scaled by 1/8 (exact in bf16); stride 80 shorts
#pragma unroll
    for (int hh = 0; hh < 2; ++hh) {
        const unsigned short* qsrc =
            qkvn + (size_t)(b * 2048 + qb * 64 + srow) * 1152 + 128 + (hp * 2 + hh) * 64 + schunk * 8;
        s16x8 v = *(const s16x8*)qsrc;
#pragma unroll
        for (int e = 0; e < 8; ++e)
            v[e] = (short)f2bf(bf2f((unsigned short)v[e]) * 0.125f);
        *(s16x8*)&Qs[(hh * 64 + srow) * 80 + schunk * 8] = v;
    }
    __syncthreads();
    s16x8 qfr[2][2];
#pragma unroll
    for (int qf = 0; qf < 2; ++qf)
#pragma unroll
        for (int dh = 0; dh < 2; ++dh)
            qfr[qf][dh] = *(const s16x8*)&Qs[(hl * 64 + qhalf * 32 + qf * 16 + col) * 80 + dh * 32 + quad * 8];

    // stage K/V tile 0 (global reads linear; LDS writes swizzled)
    const unsigned short* kbase = qkvn + (size_t)(b * 2048 + srow) * 1152 + schunk * 8;  // + kb*64*1152
    const unsigned short* vbase = vT + (size_t)(b * 64 + srow) * 2048 + schunk * 8;      // + kb*64
    *(uint4*)&Ks0[ldsoff] = *(const uint4*)(kbase);
    *(uint4*)&Vt0[ldsoff] = *(const uint4*)(vbase);
    __syncthreads();  // KV0 visible; all Q-frag reads done -> PQ reusable as P

    const int c7 = col & 7;
    const int koff0 = (kpar * 32 + col) * 128 + ((quad ^ c7) * 16);
    const int koff1 = (kpar * 32 + col) * 128 + (((4 + quad) ^ c7) * 16);
    const int voff = col * 128 + (((kpar * 4 + quad) ^ c7) * 16);

    f32x4 Oacc[4][2];     // [d-subtile][q-frag] of O^T[d][q]
    float psum[2] = {0.f, 0.f};  // [q-frag] partial l (this lane's k-share)
#pragma unroll
    for (int ds = 0; ds < 4; ++ds)
#pragma unroll
        for (int qf = 0; qf < 2; ++qf) Oacc[ds][qf] = (f32x4){0.f, 0.f, 0.f, 0.f};

    const int qbase = qb * 64 + qhalf * 32;   // + qf*16 + col = this lane's q rows

    for (int kb = 0; kb <= qb; ++kb) {
        const int p = kb & 1;
        uint4 kreg, vreg;
        if (kb < qb) {  // issue next tile's global loads before compute
            kreg = *(const uint4*)(kbase + (size_t)(kb + 1) * 64 * 1152);
            vreg = *(const uint4*)(vbase + (kb + 1) * 64);
        }
        const bool diag = (kb == qb);
        if (!(diag && kpar == 1 && qhalf == 0)) {
            const bool needmask = diag && (kpar == qhalf);
            const char* kb8 = (const char*)(Ks0 + p * 4096);
            const char* vb8 = (const char*)(Vt0 + p * 4096);

#pragma unroll
            for (int nt = 0; nt < 2; ++nt) {
                const s16x8 kf0 = *(const s16x8*)(kb8 + nt * 2048 + koff0);
                const s16x8 kf1 = *(const s16x8*)(kb8 + nt * 2048 + koff1);
#pragma unroll
                for (int qf = 0; qf < 2; ++qf) {
                    f32x4 z = (f32x4){-12.f, -12.f, -12.f, -12.f};  // exp bias via C-in
                    z = MFMA16(kf0, qfr[qf][0], z);   // A=K, B=Q -> S^T[k][q] - 12
                    z = MFMA16(kf1, qfr[qf][1], z);
                    const int qg = qbase + qf * 16 + col;
                    const int kl = kb * 64 + kpar * 32 + nt * 16 + quad * 4;
                    float ev[4];
#pragma unroll
                    for (int r = 0; r < 4; ++r) {
                        float sv = z[r];
                        if (needmask && (kl + r > qg)) sv = -1e30f;
                        ev[r] = __expf(sv);
                    }
                    psum[qf] += (ev[0] + ev[1]) + (ev[2] + ev[3]);  // l partial in VALU
                    unsigned int plo, phi;
                    asm("v_cvt_pk_bf16_f32 %0, %1, %2" : "=v"(plo) : "v"(ev[0]), "v"(ev[1]));
                    asm("v_cvt_pk_bf16_f32 %0, %1, %2" : "=v"(phi) : "v"(ev[2]), "v"(ev[3]));
                    uint2 pk2;
                    pk2.x = plo; pk2.y = phi;
                    *(uint2*)&Ps[(qf * 16 + col) * 40 + nt * 16 + quad * 4] = pk2;  // 8B, k-contig
                }
            }

            const s16x8 pf0 = *(const s16x8*)&Ps[col * 40 + quad * 8];          // B: P[q][k]
            const s16x8 pf1 = *(const s16x8*)&Ps[(16 + col) * 40 + quad * 8];
            __builtin_amdgcn_s_setprio(1);
#pragma unroll
            for (int ds = 0; ds < 4; ++ds) {
                const s16x8 vf = *(const s16x8*)(vb8 + ds * 2048 + voff);
                Oacc[ds][0] = MFMA16(vf, pf0, Oacc[ds][0]);   // A=V^T, B=P^T -> O^T[d][q]
                Oacc[ds][1] = MFMA16(vf, pf1, Oacc[ds][1]);
            }
            __builtin_amdgcn_s_setprio(0);
        }

        if (kb < qb) {  // LDS-write prefetched tile into the other (swizzled) buffer
            *(uint4*)&Ks0[(p ^ 1) * 4096 + ldsoff] = kreg;
            *(uint4*)&Vt0[(p ^ 1) * 4096 + ldsoff] = vreg;
        }
        __syncthreads();  // ONE barrier per iter
    }

    // finish l: each lane's psum covers its quad's k-rows; reduce across quads
#pragma unroll
    for (int qf = 0; qf < 2; ++qf) {
        psum[qf] += __shfl_xor(psum[qf], 16);
        psum[qf] += __shfl_xor(psum[qf], 32);
    }

    // ---- epilogue: merge k-split partials of wave pair (w, w^1) through LDS ----
    float* mg = (float*)SM + (hl * 2 + qhalf) * 2112;
    float* lm = (float*)(SM + 33792) + (hl * 2 + qhalf) * 32;
    if (kpar) {
#pragma unroll
        for (int ds = 0; ds < 4; ++ds)
#pragma unroll
            for (int qf = 0; qf < 2; ++qf)
#pragma unroll
                for (int r = 0; r < 4; ++r)
                    mg[(ds * 16 + quad * 4 + r) * 33 + qf * 16 + col] = Oacc[ds][qf][r];
        if (quad == 0) { lm[col] = psum[0]; lm[16 + col] = psum[1]; }
    }
    __syncthreads();
    if (!kpar) {
        const int h = hp * 2 + hl;
#pragma unroll
        for (int qf = 0; qf < 2; ++qf) {
            const int qglob = qbase + qf * 16 + col;
            const float inv = 1.0f / (psum[qf] + lm[qf * 16 + col]);
            const size_t base = (((size_t)b * 2048 + qglob) * 16 + h) * 64 + quad * 4;
#pragma unroll
            for (int ds = 0; ds < 4; ++ds) {
                ushort4 ov;
                unsigned short* op = (unsigned short*)&ov;
#pragma unroll
                for (int r = 0; r < 4; ++r)
                    op[r] = f2bf((Oacc[ds][qf][r] + mg[(ds * 16 + quad * 4 + r) * 33 + qf * 16 + col]) * inv);
                *(ushort4*)&obuf[base + ds * 16] = ov;  // 8B packed store, d-contig
            }
        }
    }
}

// ---------- launch ----------
extern "C" void kernel_launch(void* const* d_in, const int* in_sizes, int n_in,
                              void* d_out, int out_size, void* d_ws, size_t ws_size,
                              hipStream_t stream) {
    (void)in_sizes; (void)n_in; (void)out_size; (void)ws_size;
    const float* x     = (const float*)d_in[0];  // (2,2048,1024) fp32
    const float* Wqkv  = (const float*)d_in[1];  // (1152,1024)  fp32
    const float* gamma = (const float*)d_in[2];  // (1152,)      fp32
    const float* beta  = (const float*)d_in[3];  // (1152,)      fp32
    const float* Wfc   = (const float*)d_in[4];  // (1024,1024)  fp32
    float* out = (float*)d_out;                  // (2,2048,1024) fp32

    // ws >= 22,806,528 B (proven in round 5)
    char* ws = (char*)d_ws;
    unsigned short* xb   = (unsigned short*)ws;               // 8,388,608
    unsigned short* Wqb  = (unsigned short*)(ws + 8388608);   // 2,359,296
    unsigned short* Wfb  = (unsigned short*)(ws + 10747904);  // 2,097,152
    unsigned short* qkvn = (unsigned short*)(ws + 12845056);  // 9,437,184
    unsigned short* vT   = (unsigned short*)(ws + 22282240);  //   524,288
    unsigned short* abuf = (unsigned short*)ws;               // alias xb (dead after gemm1)

    cvt_all<<<dim3(3136), 256, 0, stream>>>(x, Wqkv, Wfc, xb, Wqb, Wfb);
    gemm_mn<false><<<dim3(576), 512, 0, stream>>>(xb, Wqb, qkvn, 1024, 1152);
    ln_row<<<dim3(4096), 64, 0, stream>>>(qkvn, gamma, beta, vT);
    attn_kernel<<<dim3(16, 32), 512, 0, stream>>>(qkvn, vT, abuf);
    gemm_mn<true><<<dim3(512), 512, 0, stream>>>(abuf, Wfb, out, 1024, 1024);
}

// Round 10
// 145.576 us; speedup vs baseline: 2.0769x; 1.0009x over previous
//
#include <hip/hip_runtime.h>
#include <stdint.h>

typedef __attribute__((ext_vector_type(8))) short s16x8;
typedef __attribute__((ext_vector_type(4))) float f32x4;

#define MFMA16(a, b, c) __builtin_amdgcn_mfma_f32_16x16x32_bf16((a), (b), (c), 0, 0, 0)

// ---------- helpers ----------
__device__ __forceinline__ unsigned short f2bf(float f) {
    unsigned int u = __float_as_uint(f);
    return (unsigned short)((u + 0x7FFFu + ((u >> 16) & 1u)) >> 16);
}
__device__ __forceinline__ float bf2f(unsigned short h) {
    return __uint_as_float(((unsigned int)h) << 16);
}
__device__ __forceinline__ void cvt8(unsigned short* dst, const float* src) {
    const float4 f0 = *(const float4*)(src);
    const float4 f1 = *(const float4*)(src + 4);
    s16x8 v;
    v[0] = (short)f2bf(f0.x); v[1] = (short)f2bf(f0.y);
    v[2] = (short)f2bf(f0.z); v[3] = (short)f2bf(f0.w);
    v[4] = (short)f2bf(f1.x); v[5] = (short)f2bf(f1.y);
    v[6] = (short)f2bf(f1.z); v[7] = (short)f2bf(f1.w);
    *(s16x8*)dst = v;
}
// async global->LDS DMA, 16 B/lane; LDS base wave-uniform, lane i -> base+i*16.
__device__ __forceinline__ void gl_lds16(const unsigned short* g, unsigned short* l) {
    __builtin_amdgcn_global_load_lds(
        (const __attribute__((address_space(1))) unsigned int*)g,
        (__attribute__((address_space(3))) unsigned int*)l,
        16, 0, 0);
}

// ---------- merged fp32 -> bf16 convert for x / Wqkv / Wfc (one launch) ----------
__global__ __launch_bounds__(256) void cvt_all(const float* __restrict__ x,
                                               const float* __restrict__ wq,
                                               const float* __restrict__ wf,
                                               unsigned short* __restrict__ xb,
                                               unsigned short* __restrict__ wqb,
                                               unsigned short* __restrict__ wfb) {
    const int blk = blockIdx.x;  // 0..3135
    const float* src;
    unsigned short* dst;
    int base;
    if (blk < 2048)      { src = x;  dst = xb;  base = blk; }
    else if (blk < 2624) { src = wq; dst = wqb; base = blk - 2048; }
    else                 { src = wf; dst = wfb; base = blk - 2624; }
    const int i = (base * 256 + threadIdx.x) * 8;
    cvt8(&dst[i], &src[i]);
}

// ---------- GEMM r27 == r6 best-known: 128x64, 48KB dbuf, XCD-pinned ----------
// r8: per-block __threadfence = L2 writeback on non-coherent-L2 HW -> never
// fuse producer->consumer across blocks here; kernel boundary is the cheap fence.
// r7: lb(512,6) spills. r9 isolated attn l-psum (+2us) as the r7 regressor.
template <bool OUT_F32>
__global__ __launch_bounds__(512) void gemm_mn(const unsigned short* __restrict__ A,
                                               const unsigned short* __restrict__ Bw,
                                               void* __restrict__ Cout, int K, int N) {
    const int wg = blockIdx.x;
    const int xcd = wg & 7, j = wg >> 3;
    const int bm = (xcd << 2) + (j & 3);   // 4 A-panels per XCD (XCD = wg%8, m09/T1)
    const int bn = j >> 2;                 // all N-tiles per XCD
    const int t = threadIdx.x;
    const int lane = t & 63, w = t >> 6;          // 8 waves
    const int quad = lane >> 4, col = lane & 15;
    const int wm = (w >> 1) * 32, wn = (w & 1) * 32;  // wave = 32x32

    __shared__ alignas(16) unsigned short As[2][128 * 64];  // 2 x 16 KB, swizzled
    __shared__ alignas(16) unsigned short Bs[2][64 * 64];   // 2 x  8 KB, swizzled

    f32x4 acc[2][2];
#pragma unroll
    for (int i = 0; i < 2; ++i)
#pragma unroll
        for (int j2 = 0; j2 < 2; ++j2) acc[i][j2] = (f32x4){0.f, 0.f, 0.f, 0.f};

    const int lrow = lane >> 3;                      // 0..7
    const int lcol = ((lane & 7) ^ lrow) * 8;        // swizzled global chunk
    // wave w stages A rows [w*16, w*16+16) (2 issues) and B rows [w*8, w*8+8)
    const unsigned short* Ap = A + (size_t)(bm * 128 + w * 16 + lrow) * K + lcol;
    const unsigned short* Bp = Bw + (size_t)(bn * 64 + w * 8 + lrow) * K + lcol;

    // prime tile 0 into buffer 0
#pragma unroll
    for (int j2 = 0; j2 < 2; ++j2)
        gl_lds16(Ap + (size_t)(j2 * 8) * K, &As[0][(w * 16 + j2 * 8) * 64]);
    gl_lds16(Bp, &Bs[0][(w * 8) * 64]);
    __syncthreads();  // drain: tile 0 visible

    const int c7 = col & 7;
    const int fs0 = ((0 * 4 + quad) ^ c7) * 8;
    const int fs1 = ((1 * 4 + quad) ^ c7) * 8;

    for (int k0 = 0; k0 < K; k0 += 64) {
        const int p = (k0 >> 6) & 1;
        if (k0 + 64 < K) {  // stream next tile into the other buffer (no drain)
#pragma unroll
            for (int j2 = 0; j2 < 2; ++j2)
                gl_lds16(Ap + (size_t)(j2 * 8) * K + k0 + 64, &As[p ^ 1][(w * 16 + j2 * 8) * 64]);
            gl_lds16(Bp + k0 + 64, &Bs[p ^ 1][(w * 8) * 64]);
        }
        // hoist ALL 8 fragment loads, then run the 8 MFMAs
        s16x8 af[2][2], bfr[2][2];
#pragma unroll
        for (int s = 0; s < 2; ++s) {
            const int fs = s ? fs1 : fs0;
#pragma unroll
            for (int i = 0; i < 2; ++i)
                af[s][i] = *(const s16x8*)&As[p][(wm + i * 16 + col) * 64 + fs];
#pragma unroll
            for (int j2 = 0; j2 < 2; ++j2)
                bfr[s][j2] = *(const s16x8*)&Bs[p][(wn + j2 * 16 + col) * 64 + fs];
        }
#pragma unroll
        for (int s = 0; s < 2; ++s)
#pragma unroll
            for (int i = 0; i < 2; ++i)
#pragma unroll
                for (int j2 = 0; j2 < 2; ++j2)
                    acc[i][j2] = MFMA16(af[s][i], bfr[s][j2], acc[i][j2]);
        __syncthreads();
    }
    const int rowb = bm * 128 + wm + quad * 4;
    const int colb = bn * 64 + wn + col;
#pragma unroll
    for (int i = 0; i < 2; ++i)
#pragma unroll
        for (int j2 = 0; j2 < 2; ++j2)
#pragma unroll
            for (int r = 0; r < 4; ++r) {
                size_t off = (size_t)(rowb + i * 16 + r) * N + colb + j2 * 16;
                if (OUT_F32) ((float*)Cout)[off] = acc[i][j2][r];
                else ((unsigned short*)Cout)[off] = f2bf(acc[i][j2][r]);
            }
}

// ---------- LayerNorm r27: 8 waves/block (512 blocks) + Q-scale fold ----------
// One wave per row as before, but 8 rows per block -> 8x fewer dispatches.
// Columns >=128 (the Q heads) are multiplied by 0.125 BEFORE the bf16 round:
// pow-2 scaling commutes with RNE, so Q fragments are bit-identical to the old
// round-then-scale in the attn prologue — which becomes a pure copy.
__global__ __launch_bounds__(512) void ln_row(unsigned short* __restrict__ qkvn,
                                              const float* __restrict__ gamma,
                                              const float* __restrict__ beta,
                                              unsigned short* __restrict__ vT) {
    const int row = blockIdx.x * 8 + (threadIdx.x >> 6);  // b*2048 + l
    const int b = row >> 11, l = row & 2047;
    unsigned short* rp = qkvn + (size_t)row * 1152;
    const int lane = threadIdx.x & 63;

    s16x8 v0 = *(const s16x8*)&rp[lane * 8];
    s16x8 v1 = *(const s16x8*)&rp[512 + lane * 8];
    unsigned int v2u = *(const unsigned int*)&rp[1024 + lane * 2];

    float f0[8], f1[8], f2[2];
    float s = 0.f, s2 = 0.f;
#pragma unroll
    for (int e = 0; e < 8; ++e) {
        f0[e] = bf2f((unsigned short)v0[e]);
        f1[e] = bf2f((unsigned short)v1[e]);
        s += f0[e] + f1[e];
        s2 += f0[e] * f0[e] + f1[e] * f1[e];
    }
    f2[0] = bf2f((unsigned short)(v2u & 0xFFFF));
    f2[1] = bf2f((unsigned short)(v2u >> 16));
    s += f2[0] + f2[1];
    s2 += f2[0] * f2[0] + f2[1] * f2[1];

#pragma unroll
    for (int off = 1; off < 64; off <<= 1) {
        s += __shfl_xor(s, off);
        s2 += __shfl_xor(s2, off);
    }
    const float mu = s * (1.0f / 1152.0f);
    float var = s2 * (1.0f / 1152.0f) - mu * mu;
    var = fmaxf(var, 0.0f);
    const float rstd = rsqrtf(var + 1e-5f);

    {
        const float qs = (lane >= 16) ? 0.125f : 1.0f;  // cols >=128 are Q heads
        s16x8 o, oq;
#pragma unroll
        for (int e = 0; e < 8; ++e) {
            const float y = (f0[e] - mu) * rstd * gamma[lane * 8 + e] + beta[lane * 8 + e];
            o[e] = (short)f2bf(y);
            oq[e] = (short)f2bf(y * qs);
        }
        *(s16x8*)&rp[lane * 8] = (lane >= 16) ? oq : o;
        if (lane >= 8 && lane < 16) {  // v head (cols 64..127) -> transposed copy
            const int d0 = lane * 8 - 64;
#pragma unroll
            for (int e = 0; e < 8; ++e)
                vT[((size_t)(b * 64 + d0 + e)) * 2048 + l] = (unsigned short)o[e];
        }
    }
    {
        s16x8 o;
#pragma unroll
        for (int e = 0; e < 8; ++e)
            o[e] = (short)f2bf(((f1[e] - mu) * rstd * gamma[512 + lane * 8 + e] + beta[512 + lane * 8 + e]) * 0.125f);
        *(s16x8*)&rp[512 + lane * 8] = o;
    }
    {
        unsigned short o0 = f2bf(((f2[0] - mu) * rstd * gamma[1024 + lane * 2] + beta[1024 + lane * 2]) * 0.125f);
        unsigned short o1 = f2bf(((f2[1] - mu) * rstd * gamma[1025 + lane * 2] + beta[1025 + lane * 2]) * 0.125f);
        *(unsigned int*)&rp[1024 + lane * 2] = ((unsigned int)o1 << 16) | o0;
    }
}

// ---------- Flash-style causal MQA — r27: r6 structure, Q pre-scaled upstream ----------
// l is accumulated via the ones-MFMA again (r9 isolated l-psum as +2us: the
// VALU adds sat on the critical softmax chain while the MFMA pipe idled).
// Q staging is now a pure copy (scale folded into ln_row, bit-identical).
__global__ __launch_bounds__(512, 4) void attn_kernel(const unsigned short* __restrict__ qkvn,
                                                      const unsigned short* __restrict__ vT,
                                                      unsigned short* __restrict__ obuf) {
    const int b = blockIdx.x >> 3, hp = blockIdx.x & 7;
    const int yy = blockIdx.y;
    const int qb = (yy < 16) ? (31 - yy) : (yy - 16);  // CU-paired: (31-a)+a = 33 iters/CU
    const int t = threadIdx.x;
    const int lane = t & 63, w = t >> 6;
    const int quad = lane >> 4, col = lane & 15;
    const int hl = w >> 2;              // head-local 0/1
    const int qhalf = (w >> 1) & 1;     // 32-q group within head
    const int kpar = w & 1;             // k-half of the 64-k tile

    __shared__ alignas(16) unsigned char SM[53248];
    unsigned short* Ks0 = (unsigned short*)SM;             // 8192 shorts
    unsigned short* Vt0 = (unsigned short*)(SM + 16384);   // 8192 shorts
    unsigned short* Qs  = (unsigned short*)(SM + 32768);   // [128][80] prologue view
    unsigned short* Ps  = (unsigned short*)(SM + 32768) + w * 1280;  // per-wave [32][40]

    const int srow = t >> 3;                  // 0..63
    const int schunk = t & 7;                 // global 8-short chunk
    const int ldsoff = srow * 64 + (schunk ^ (srow & 7)) * 8;  // swizzled LDS addr (shorts)

    // stage Q for both heads (already scaled by 1/8 in ln_row) — pure copy
#pragma unroll
    for (int hh = 0; hh < 2; ++hh) {
        const unsigned short* qsrc =
            qkvn + (size_t)(b * 2048 + qb * 64 + srow) * 1152 + 128 + (hp * 2 + hh) * 64 + schunk * 8;
        *(s16x8*)&Qs[(hh * 64 + srow) * 80 + schunk * 8] = *(const s16x8*)qsrc;
    }
    __syncthreads();
    s16x8 qfr[2][2];
#pragma unroll
    for (int qf = 0; qf < 2; ++qf)
#pragma unroll
        for (int dh = 0; dh < 2; ++dh)
            qfr[qf][dh] = *(const s16x8*)&Qs[(hl * 64 + qhalf * 32 + qf * 16 + col) * 80 + dh * 32 + quad * 8];

    // stage K/V tile 0 (global reads linear; LDS writes swizzled)
    const unsigned short* kbase = qkvn + (size_t)(b * 2048 + srow) * 1152 + schunk * 8;  // + kb*64*1152
    const unsigned short* vbase = vT + (size_t)(b * 64 + srow) * 2048 + schunk * 8;      // + kb*64
    *(uint4*)&Ks0[ldsoff] = *(const uint4*)(kbase);
    *(uint4*)&Vt0[ldsoff] = *(const uint4*)(vbase);
    __syncthreads();  // KV0 visible; all Q-frag reads done -> PQ reusable as P

    const int c7 = col & 7;
    const int koff0 = (kpar * 32 + col) * 128 + ((quad ^ c7) * 16);
    const int koff1 = (kpar * 32 + col) * 128 + (((4 + quad) ^ c7) * 16);
    const int voff = col * 128 + (((kpar * 4 + quad) ^ c7) * 16);

    s16x8 ones;
#pragma unroll
    for (int e = 0; e < 8; ++e) ones[e] = (short)0x3F80;  // bf16 1.0

    f32x4 Oacc[4][2];     // [d-subtile][q-frag] of O^T[d][q]
    f32x4 lacc[2];        // [q-frag]
#pragma unroll
    for (int ds = 0; ds < 4; ++ds)
#pragma unroll
        for (int qf = 0; qf < 2; ++qf) Oacc[ds][qf] = (f32x4){0.f, 0.f, 0.f, 0.f};
    lacc[0] = (f32x4){0.f, 0.f, 0.f, 0.f};
    lacc[1] = (f32x4){0.f, 0.f, 0.f, 0.f};

    const int qbase = qb * 64 + qhalf * 32;   // + qf*16 + col = this lane's q rows

    for (int kb = 0; kb <= qb; ++kb) {
        const int p = kb & 1;
        uint4 kreg, vreg;
        if (kb < qb) {  // issue next tile's global loads before compute
            kreg = *(const uint4*)(kbase + (size_t)(kb + 1) * 64 * 1152);
            vreg = *(const uint4*)(vbase + (kb + 1) * 64);
        }
        const bool diag = (kb == qb);
        if (!(diag && kpar == 1 && qhalf == 0)) {
            const bool needmask = diag && (kpar == qhalf);
            const char* kb8 = (const char*)(Ks0 + p * 4096);
            const char* vb8 = (const char*)(Vt0 + p * 4096);

#pragma unroll
            for (int nt = 0; nt < 2; ++nt) {
                const s16x8 kf0 = *(const s16x8*)(kb8 + nt * 2048 + koff0);
                const s16x8 kf1 = *(const s16x8*)(kb8 + nt * 2048 + koff1);
#pragma unroll
                for (int qf = 0; qf < 2; ++qf) {
                    f32x4 z = (f32x4){-12.f, -12.f, -12.f, -12.f};  // exp bias via C-in
                    z = MFMA16(kf0, qfr[qf][0], z);   // A=K, B=Q -> S^T[k][q] - 12
                    z = MFMA16(kf1, qfr[qf][1], z);
                    const int qg = qbase + qf * 16 + col;
                    const int kl = kb * 64 + kpar * 32 + nt * 16 + quad * 4;
                    float ev[4];
#pragma unroll
                    for (int r = 0; r < 4; ++r) {
                        float sv = z[r];
                        if (needmask && (kl + r > qg)) sv = -1e30f;
                        ev[r] = __expf(sv);
                    }
                    unsigned int plo, phi;
                    asm("v_cvt_pk_bf16_f32 %0, %1, %2" : "=v"(plo) : "v"(ev[0]), "v"(ev[1]));
                    asm("v_cvt_pk_bf16_f32 %0, %1, %2" : "=v"(phi) : "v"(ev[2]), "v"(ev[3]));
                    uint2 pk2;
                    pk2.x = plo; pk2.y = phi;
                    *(uint2*)&Ps[(qf * 16 + col) * 40 + nt * 16 + quad * 4] = pk2;  // 8B, k-contig
                }
            }

            const s16x8 pf0 = *(const s16x8*)&Ps[col * 40 + quad * 8];          // B: P[q][k]
            const s16x8 pf1 = *(const s16x8*)&Ps[(16 + col) * 40 + quad * 8];
            __builtin_amdgcn_s_setprio(1);
            lacc[0] = MFMA16(ones, pf0, lacc[0]);   // D[*][q] = partial l[q] (idle MFMA pipe)
            lacc[1] = MFMA16(ones, pf1, lacc[1]);
#pragma unroll
            for (int ds = 0; ds < 4; ++ds) {
                const s16x8 vf = *(const s16x8*)(vb8 + ds * 2048 + voff);
                Oacc[ds][0] = MFMA16(vf, pf0, Oacc[ds][0]);   // A=V^T, B=P^T -> O^T[d][q]
                Oacc[ds][1] = MFMA16(vf, pf1, Oacc[ds][1]);
            }
            __builtin_amdgcn_s_setprio(0);
        }

        if (kb < qb) {  // LDS-write prefetched tile into the other (swizzled) buffer
            *(uint4*)&Ks0[(p ^ 1) * 4096 + ldsoff] = kreg;
            *(uint4*)&Vt0[(p ^ 1) * 4096 + ldsoff] = vreg;
        }
        __syncthreads();  // ONE barrier per iter
    }

    // ---- epilogue: merge k-split partials of wave pair (w, w^1) through LDS ----
    float* mg = (float*)SM + (hl * 2 + qhalf) * 2112;
    float* lm = (float*)(SM + 33792) + (hl * 2 + qhalf) * 32;
    if (kpar) {
#pragma unroll
        for (int ds = 0; ds < 4; ++ds)
#pragma unroll
            for (int qf = 0; qf < 2; ++qf)
#pragma unroll
                for (int r = 0; r < 4; ++r)
                    mg[(ds * 16 + quad * 4 + r) * 33 + qf * 16 + col] = Oacc[ds][qf][r];
        if (quad == 0) { lm[col] = lacc[0][0]; lm[16 + col] = lacc[1][0]; }
    }
    __syncthreads();
    if (!kpar) {
        const int h = hp * 2 + hl;
#pragma unroll
        for (int qf = 0; qf < 2; ++qf) {
            const int qglob = qbase + qf * 16 + col;
            const float inv = 1.0f / (lacc[qf][0] + lm[qf * 16 + col]);
            const size_t base = (((size_t)b * 2048 + qglob) * 16 + h) * 64 + quad * 4;
#pragma unroll
            for (int ds = 0; ds < 4; ++ds) {
                ushort4 ov;
                unsigned short* op = (unsigned short*)&ov;
#pragma unroll
                for (int r = 0; r < 4; ++r)
                    op[r] = f2bf((Oacc[ds][qf][r] + mg[(ds * 16 + quad * 4 + r) * 33 + qf * 16 + col]) * inv);
                *(ushort4*)&obuf[base + ds * 16] = ov;  // 8B packed store, d-contig
            }
        }
    }
}

// ---------- launch ----------
extern "C" void kernel_launch(void* const* d_in, const int* in_sizes, int n_in,
                              void* d_out, int out_size, void* d_ws, size_t ws_size,
                              hipStream_t stream) {
    (void)in_sizes; (void)n_in; (void)out_size; (void)ws_size;
    const float* x     = (const float*)d_in[0];  // (2,2048,1024) fp32
    const float* Wqkv  = (const float*)d_in[1];  // (1152,1024)  fp32
    const float* gamma = (const float*)d_in[2];  // (1152,)      fp32
    const float* beta  = (const float*)d_in[3];  // (1152,)      fp32
    const float* Wfc   = (const float*)d_in[4];  // (1024,1024)  fp32
    float* out = (float*)d_out;                  // (2,2048,1024) fp32

    // ws >= 22,806,528 B (proven in round 5)
    char* ws = (char*)d_ws;
    unsigned short* xb   = (unsigned short*)ws;               // 8,388,608
    unsigned short* Wqb  = (unsigned short*)(ws + 8388608);   // 2,359,296
    unsigned short* Wfb  = (unsigned short*)(ws + 10747904);  // 2,097,152
    unsigned short* qkvn = (unsigned short*)(ws + 12845056);  // 9,437,184
    unsigned short* vT   = (unsigned short*)(ws + 22282240);  //   524,288
    unsigned short* abuf = (unsigned short*)ws;               // alias xb (dead after gemm1)

    cvt_all<<<dim3(3136), 256, 0, stream>>>(x, Wqkv, Wfc, xb, Wqb, Wfb);
    gemm_mn<false><<<dim3(576), 512, 0, stream>>>(xb, Wqb, qkvn, 1024, 1152);
    ln_row<<<dim3(512), 512, 0, stream>>>(qkvn, gamma, beta, vT);
    attn_kernel<<<dim3(16, 32), 512, 0, stream>>>(qkvn, vT, abuf);
    gemm_mn<true><<<dim3(512), 512, 0, stream>>>(abuf, Wfb, out, 1024, 1024);
}

// Round 11
// 143.041 us; speedup vs baseline: 2.1137x; 1.0177x over previous
//
#include <hip/hip_runtime.h>
#include <stdint.h>

typedef __attribute__((ext_vector_type(8))) short s16x8;
typedef __attribute__((ext_vector_type(4))) float f32x4;

#define MFMA16(a, b, c) __builtin_amdgcn_mfma_f32_16x16x32_bf16((a), (b), (c), 0, 0, 0)

// ---------- helpers ----------
__device__ __forceinline__ unsigned short f2bf(float f) {
    unsigned int u = __float_as_uint(f);
    return (unsigned short)((u + 0x7FFFu + ((u >> 16) & 1u)) >> 16);
}
__device__ __forceinline__ float bf2f(unsigned short h) {
    return __uint_as_float(((unsigned int)h) << 16);
}
__device__ __forceinline__ void cvt8(unsigned short* dst, const float* src) {
    const float4 f0 = *(const float4*)(src);
    const float4 f1 = *(const float4*)(src + 4);
    s16x8 v;
    v[0] = (short)f2bf(f0.x); v[1] = (short)f2bf(f0.y);
    v[2] = (short)f2bf(f0.z); v[3] = (short)f2bf(f0.w);
    v[4] = (short)f2bf(f1.x); v[5] = (short)f2bf(f1.y);
    v[6] = (short)f2bf(f1.z); v[7] = (short)f2bf(f1.w);
    *(s16x8*)dst = v;
}
// async global->LDS DMA, 16 B/lane; LDS base wave-uniform, lane i -> base+i*16.
__device__ __forceinline__ void gl_lds16(const unsigned short* g, unsigned short* l) {
    __builtin_amdgcn_global_load_lds(
        (const __attribute__((address_space(1))) unsigned int*)g,
        (__attribute__((address_space(3))) unsigned int*)l,
        16, 0, 0);
}

// ---------- merged fp32 -> bf16 convert for x / Wqkv / Wfc (one launch) ----------
__global__ __launch_bounds__(256) void cvt_all(const float* __restrict__ x,
                                               const float* __restrict__ wq,
                                               const float* __restrict__ wf,
                                               unsigned short* __restrict__ xb,
                                               unsigned short* __restrict__ wqb,
                                               unsigned short* __restrict__ wfb) {
    const int blk = blockIdx.x;  // 0..3135
    const float* src;
    unsigned short* dst;
    int base;
    if (blk < 2048)      { src = x;  dst = xb;  base = blk; }
    else if (blk < 2624) { src = wq; dst = wqb; base = blk - 2048; }
    else                 { src = wf; dst = wfb; base = blk - 2624; }
    const int i = (base * 256 + threadIdx.x) * 8;
    cvt8(&dst[i], &src[i]);
}

// ---------- GEMM (r6 best-known): 128x64, 48KB dbuf, 3 blk/CU, XCD-pinned ----------
// Session lessons baked in: (r1/r19) deeper pipelines cost occupancy (72KB LDS
// -> 2 blk/CU -> +10us); (r22) 128x128 tile -> makespan tail; (r7) lb(512,6)
// spills at the 85-VGPR cliff; (r8) per-block __threadfence = L2 writeback on
// non-coherent-L2 HW (+157us) -> kernel boundary is the cheap fence; (r23)
// XCD-pinned decode (wg%8 = XCD, m09/T1) makes the per-XCD operand set
// (A 1MB + B <=2.4MB) L2-resident -> best measured config (143.7us).
template <bool OUT_F32>
__global__ __launch_bounds__(512) void gemm_mn(const unsigned short* __restrict__ A,
                                               const unsigned short* __restrict__ Bw,
                                               void* __restrict__ Cout, int K, int N) {
    const int wg = blockIdx.x;
    const int xcd = wg & 7, j = wg >> 3;
    const int bm = (xcd << 2) + (j & 3);   // 4 A-panels per XCD
    const int bn = j >> 2;                 // all N-tiles per XCD
    const int t = threadIdx.x;
    const int lane = t & 63, w = t >> 6;          // 8 waves
    const int quad = lane >> 4, col = lane & 15;
    const int wm = (w >> 1) * 32, wn = (w & 1) * 32;  // wave = 32x32

    __shared__ alignas(16) unsigned short As[2][128 * 64];  // 2 x 16 KB, swizzled
    __shared__ alignas(16) unsigned short Bs[2][64 * 64];   // 2 x  8 KB, swizzled

    f32x4 acc[2][2];
#pragma unroll
    for (int i = 0; i < 2; ++i)
#pragma unroll
        for (int j2 = 0; j2 < 2; ++j2) acc[i][j2] = (f32x4){0.f, 0.f, 0.f, 0.f};

    const int lrow = lane >> 3;                      // 0..7
    const int lcol = ((lane & 7) ^ lrow) * 8;        // swizzled global chunk
    // wave w stages A rows [w*16, w*16+16) (2 issues) and B rows [w*8, w*8+8)
    const unsigned short* Ap = A + (size_t)(bm * 128 + w * 16 + lrow) * K + lcol;
    const unsigned short* Bp = Bw + (size_t)(bn * 64 + w * 8 + lrow) * K + lcol;

    // prime tile 0 into buffer 0
#pragma unroll
    for (int j2 = 0; j2 < 2; ++j2)
        gl_lds16(Ap + (size_t)(j2 * 8) * K, &As[0][(w * 16 + j2 * 8) * 64]);
    gl_lds16(Bp, &Bs[0][(w * 8) * 64]);
    __syncthreads();  // drain: tile 0 visible

    const int c7 = col & 7;
    const int fs0 = ((0 * 4 + quad) ^ c7) * 8;
    const int fs1 = ((1 * 4 + quad) ^ c7) * 8;

    for (int k0 = 0; k0 < K; k0 += 64) {
        const int p = (k0 >> 6) & 1;
        if (k0 + 64 < K) {  // stream next tile into the other buffer (no drain)
#pragma unroll
            for (int j2 = 0; j2 < 2; ++j2)
                gl_lds16(Ap + (size_t)(j2 * 8) * K + k0 + 64, &As[p ^ 1][(w * 16 + j2 * 8) * 64]);
            gl_lds16(Bp + k0 + 64, &Bs[p ^ 1][(w * 8) * 64]);
        }
        // hoist ALL 8 fragment loads, then run the 8 MFMAs
        s16x8 af[2][2], bfr[2][2];
#pragma unroll
        for (int s = 0; s < 2; ++s) {
            const int fs = s ? fs1 : fs0;
#pragma unroll
            for (int i = 0; i < 2; ++i)
                af[s][i] = *(const s16x8*)&As[p][(wm + i * 16 + col) * 64 + fs];
#pragma unroll
            for (int j2 = 0; j2 < 2; ++j2)
                bfr[s][j2] = *(const s16x8*)&Bs[p][(wn + j2 * 16 + col) * 64 + fs];
        }
#pragma unroll
        for (int s = 0; s < 2; ++s)
#pragma unroll
            for (int i = 0; i < 2; ++i)
#pragma unroll
                for (int j2 = 0; j2 < 2; ++j2)
                    acc[i][j2] = MFMA16(af[s][i], bfr[s][j2], acc[i][j2]);
        __syncthreads();
    }
    const int rowb = bm * 128 + wm + quad * 4;
    const int colb = bn * 64 + wn + col;
#pragma unroll
    for (int i = 0; i < 2; ++i)
#pragma unroll
        for (int j2 = 0; j2 < 2; ++j2)
#pragma unroll
            for (int r = 0; r < 4; ++r) {
                size_t off = (size_t)(rowb + i * 16 + r) * N + colb + j2 * 16;
                if (OUT_F32) ((float*)Cout)[off] = acc[i][j2][r];
                else ((unsigned short*)Cout)[off] = f2bf(acc[i][j2][r]);
            }
}

// ---------- LayerNorm over 1152, one WAVE per row (r6 version) ----------
__global__ __launch_bounds__(64) void ln_row(unsigned short* __restrict__ qkvn,
                                             const float* __restrict__ gamma,
                                             const float* __restrict__ beta,
                                             unsigned short* __restrict__ vT) {
    const int row = blockIdx.x;  // b*2048 + l
    const int b = row >> 11, l = row & 2047;
    unsigned short* rp = qkvn + (size_t)row * 1152;
    const int lane = threadIdx.x;

    s16x8 v0 = *(const s16x8*)&rp[lane * 8];
    s16x8 v1 = *(const s16x8*)&rp[512 + lane * 8];
    unsigned int v2u = *(const unsigned int*)&rp[1024 + lane * 2];

    float f0[8], f1[8], f2[2];
    float s = 0.f, s2 = 0.f;
#pragma unroll
    for (int e = 0; e < 8; ++e) {
        f0[e] = bf2f((unsigned short)v0[e]);
        f1[e] = bf2f((unsigned short)v1[e]);
        s += f0[e] + f1[e];
        s2 += f0[e] * f0[e] + f1[e] * f1[e];
    }
    f2[0] = bf2f((unsigned short)(v2u & 0xFFFF));
    f2[1] = bf2f((unsigned short)(v2u >> 16));
    s += f2[0] + f2[1];
    s2 += f2[0] * f2[0] + f2[1] * f2[1];

#pragma unroll
    for (int off = 1; off < 64; off <<= 1) {
        s += __shfl_xor(s, off);
        s2 += __shfl_xor(s2, off);
    }
    const float mu = s * (1.0f / 1152.0f);
    float var = s2 * (1.0f / 1152.0f) - mu * mu;
    var = fmaxf(var, 0.0f);
    const float rstd = rsqrtf(var + 1e-5f);

    {
        s16x8 o;
#pragma unroll
        for (int e = 0; e < 8; ++e)
            o[e] = (short)f2bf((f0[e] - mu) * rstd * gamma[lane * 8 + e] + beta[lane * 8 + e]);
        *(s16x8*)&rp[lane * 8] = o;
        if (lane >= 8 && lane < 16) {  // v head (cols 64..127) -> transposed copy
            const int d0 = lane * 8 - 64;
#pragma unroll
            for (int e = 0; e < 8; ++e)
                vT[((size_t)(b * 64 + d0 + e)) * 2048 + l] = (unsigned short)o[e];
        }
    }
    {
        s16x8 o;
#pragma unroll
        for (int e = 0; e < 8; ++e)
            o[e] = (short)f2bf((f1[e] - mu) * rstd * gamma[512 + lane * 8 + e] + beta[512 + lane * 8 + e]);
        *(s16x8*)&rp[512 + lane * 8] = o;
    }
    {
        unsigned short o0 = f2bf((f2[0] - mu) * rstd * gamma[1024 + lane * 2] + beta[1024 + lane * 2]);
        unsigned short o1 = f2bf((f2[1] - mu) * rstd * gamma[1025 + lane * 2] + beta[1025 + lane * 2]);
        *(unsigned int*)&rp[1024 + lane * 2] = ((unsigned int)o1 << 16) | o0;
    }
}

// ---------- Flash-style causal MQA (r6 version): LDS staging + 1 barrier ----------
// 32q x 32k k-split waves; exp bias via MFMA C-in = -12; v_cvt_pk_bf16_f32
// packing; l accumulated on the idle MFMA pipe (ones-MFMA); epilogue merges
// the wave-pair k-split partials through dead LDS. Q pre-scaled 1/8 in the
// prologue (exact in bf16).
__global__ __launch_bounds__(512, 4) void attn_kernel(const unsigned short* __restrict__ qkvn,
                                                      const unsigned short* __restrict__ vT,
                                                      unsigned short* __restrict__ obuf) {
    const int b = blockIdx.x >> 3, hp = blockIdx.x & 7;
    const int yy = blockIdx.y;
    const int qb = (yy < 16) ? (31 - yy) : (yy - 16);  // CU-paired: (31-a)+a = 33 iters/CU
    const int t = threadIdx.x;
    const int lane = t & 63, w = t >> 6;
    const int quad = lane >> 4, col = lane & 15;
    const int hl = w >> 2;              // head-local 0/1
    const int qhalf = (w >> 1) & 1;     // 32-q group within head
    const int kpar = w & 1;             // k-half of the 64-k tile

    __shared__ alignas(16) unsigned char SM[53248];
    unsigned short* Ks0 = (unsigned short*)SM;             // 8192 shorts
    unsigned short* Vt0 = (unsigned short*)(SM + 16384);   // 8192 shorts
    unsigned short* Qs  = (unsigned short*)(SM + 32768);   // [128][80] prologue view
    unsigned short* Ps  = (unsigned short*)(SM + 32768) + w * 1280;  // per-wave [32][40]

    const int srow = t >> 3;                  // 0..63
    const int schunk = t & 7;                 // global 8-short chunk
    const int ldsoff = srow * 64 + (schunk ^ (srow & 7)) * 8;  // swizzled LDS addr (shorts)

    // stage Q for both heads, pre-scaled by 1/8 (exact in bf16); stride 80 shorts
#pragma unroll
    for (int hh = 0; hh < 2; ++hh) {
        const unsigned short* qsrc =
            qkvn + (size_t)(b * 2048 + qb * 64 + srow) * 1152 + 128 + (hp * 2 + hh) * 64 + schunk * 8;
        s16x8 v = *(const s16x8*)qsrc;
#pragma unroll
        for (int e = 0; e < 8; ++e)
            v[e] = (short)f2bf(bf2f((unsigned short)v[e]) * 0.125f);
        *(s16x8*)&Qs[(hh * 64 + srow) * 80 + schunk * 8] = v;
    }
    __syncthreads();
    s16x8 qfr[2][2];
#pragma unroll
    for (int qf = 0; qf < 2; ++qf)
#pragma unroll
        for (int dh = 0; dh < 2; ++dh)
            qfr[qf][dh] = *(const s16x8*)&Qs[(hl * 64 + qhalf * 32 + qf * 16 + col) * 80 + dh * 32 + quad * 8];

    // stage K/V tile 0 (global reads linear; LDS writes swizzled)
    const unsigned short* kbase = qkvn + (size_t)(b * 2048 + srow) * 1152 + schunk * 8;  // + kb*64*1152
    const unsigned short* vbase = vT + (size_t)(b * 64 + srow) * 2048 + schunk * 8;      // + kb*64
    *(uint4*)&Ks0[ldsoff] = *(const uint4*)(kbase);
    *(uint4*)&Vt0[ldsoff] = *(const uint4*)(vbase);
    __syncthreads();  // KV0 visible; all Q-frag reads done -> PQ reusable as P

    const int c7 = col & 7;
    const int koff0 = (kpar * 32 + col) * 128 + ((quad ^ c7) * 16);
    const int koff1 = (kpar * 32 + col) * 128 + (((4 + quad) ^ c7) * 16);
    const int voff = col * 128 + (((kpar * 4 + quad) ^ c7) * 16);

    s16x8 ones;
#pragma unroll
    for (int e = 0; e < 8; ++e) ones[e] = (short)0x3F80;  // bf16 1.0

    f32x4 Oacc[4][2];     // [d-subtile][q-frag] of O^T[d][q]
    f32x4 lacc[2];        // [q-frag]
#pragma unroll
    for (int ds = 0; ds < 4; ++ds)
#pragma unroll
        for (int qf = 0; qf < 2; ++qf) Oacc[ds][qf] = (f32x4){0.f, 0.f, 0.f, 0.f};
    lacc[0] = (f32x4){0.f, 0.f, 0.f, 0.f};
    lacc[1] = (f32x4){0.f, 0.f, 0.f, 0.f};

    const int qbase = qb * 64 + qhalf * 32;   // + qf*16 + col = this lane's q rows

    for (int kb = 0; kb <= qb; ++kb) {
        const int p = kb & 1;
        uint4 kreg, vreg;
        if (kb < qb) {  // issue next tile's global loads before compute
            kreg = *(const uint4*)(kbase + (size_t)(kb + 1) * 64 * 1152);
            vreg = *(const uint4*)(vbase + (kb + 1) * 64);
        }
        const bool diag = (kb == qb);
        if (!(diag && kpar == 1 && qhalf == 0)) {
            const bool needmask = diag && (kpar == qhalf);
            const char* kb8 = (const char*)(Ks0 + p * 4096);
            const char* vb8 = (const char*)(Vt0 + p * 4096);

#pragma unroll
            for (int nt = 0; nt < 2; ++nt) {
                const s16x8 kf0 = *(const s16x8*)(kb8 + nt * 2048 + koff0);
                const s16x8 kf1 = *(const s16x8*)(kb8 + nt * 2048 + koff1);
#pragma unroll
                for (int qf = 0; qf < 2; ++qf) {
                    f32x4 z = (f32x4){-12.f, -12.f, -12.f, -12.f};  // exp bias via C-in
                    z = MFMA16(kf0, qfr[qf][0], z);   // A=K, B=Q -> S^T[k][q] - 12
                    z = MFMA16(kf1, qfr[qf][1], z);
                    const int qg = qbase + qf * 16 + col;
                    const int kl = kb * 64 + kpar * 32 + nt * 16 + quad * 4;
                    float ev[4];
#pragma unroll
                    for (int r = 0; r < 4; ++r) {
                        float sv = z[r];
                        if (needmask && (kl + r > qg)) sv = -1e30f;
                        ev[r] = __expf(sv);
                    }
                    unsigned int plo, phi;
                    asm("v_cvt_pk_bf16_f32 %0, %1, %2" : "=v"(plo) : "v"(ev[0]), "v"(ev[1]));
                    asm("v_cvt_pk_bf16_f32 %0, %1, %2" : "=v"(phi) : "v"(ev[2]), "v"(ev[3]));
                    uint2 pk2;
                    pk2.x = plo; pk2.y = phi;
                    *(uint2*)&Ps[(qf * 16 + col) * 40 + nt * 16 + quad * 4] = pk2;  // 8B, k-contig
                }
            }

            const s16x8 pf0 = *(const s16x8*)&Ps[col * 40 + quad * 8];          // B: P[q][k]
            const s16x8 pf1 = *(const s16x8*)&Ps[(16 + col) * 40 + quad * 8];
            __builtin_amdgcn_s_setprio(1);
            lacc[0] = MFMA16(ones, pf0, lacc[0]);   // D[*][q] = partial l[q] (idle MFMA pipe)
            lacc[1] = MFMA16(ones, pf1, lacc[1]);
#pragma unroll
            for (int ds = 0; ds < 4; ++ds) {
                const s16x8 vf = *(const s16x8*)(vb8 + ds * 2048 + voff);
                Oacc[ds][0] = MFMA16(vf, pf0, Oacc[ds][0]);   // A=V^T, B=P^T -> O^T[d][q]
                Oacc[ds][1] = MFMA16(vf, pf1, Oacc[ds][1]);
            }
            __builtin_amdgcn_s_setprio(0);
        }

        if (kb < qb) {  // LDS-write prefetched tile into the other (swizzled) buffer
            *(uint4*)&Ks0[(p ^ 1) * 4096 + ldsoff] = kreg;
            *(uint4*)&Vt0[(p ^ 1) * 4096 + ldsoff] = vreg;
        }
        __syncthreads();  // ONE barrier per iter
    }

    // ---- epilogue: merge k-split partials of wave pair (w, w^1) through LDS ----
    float* mg = (float*)SM + (hl * 2 + qhalf) * 2112;
    float* lm = (float*)(SM + 33792) + (hl * 2 + qhalf) * 32;
    if (kpar) {
#pragma unroll
        for (int ds = 0; ds < 4; ++ds)
#pragma unroll
            for (int qf = 0; qf < 2; ++qf)
#pragma unroll
                for (int r = 0; r < 4; ++r)
                    mg[(ds * 16 + quad * 4 + r) * 33 + qf * 16 + col] = Oacc[ds][qf][r];
        if (quad == 0) { lm[col] = lacc[0][0]; lm[16 + col] = lacc[1][0]; }
    }
    __syncthreads();
    if (!kpar) {
        const int h = hp * 2 + hl;
#pragma unroll
        for (int qf = 0; qf < 2; ++qf) {
            const int qglob = qbase + qf * 16 + col;
            const float inv = 1.0f / (lacc[qf][0] + lm[qf * 16 + col]);
            const size_t base = (((size_t)b * 2048 + qglob) * 16 + h) * 64 + quad * 4;
#pragma unroll
            for (int ds = 0; ds < 4; ++ds) {
                ushort4 ov;
                unsigned short* op = (unsigned short*)&ov;
#pragma unroll
                for (int r = 0; r < 4; ++r)
                    op[r] = f2bf((Oacc[ds][qf][r] + mg[(ds * 16 + quad * 4 + r) * 33 + qf * 16 + col]) * inv);
                *(ushort4*)&obuf[base + ds * 16] = ov;  // 8B packed store, d-contig
            }
        }
    }
}

// ---------- launch ----------
extern "C" void kernel_launch(void* const* d_in, const int* in_sizes, int n_in,
                              void* d_out, int out_size, void* d_ws, size_t ws_size,
                              hipStream_t stream) {
    (void)in_sizes; (void)n_in; (void)out_size; (void)ws_size;
    const float* x     = (const float*)d_in[0];  // (2,2048,1024) fp32
    const float* Wqkv  = (const float*)d_in[1];  // (1152,1024)  fp32
    const float* gamma = (const float*)d_in[2];  // (1152,)      fp32
    const float* beta  = (const float*)d_in[3];  // (1152,)      fp32
    const float* Wfc   = (const float*)d_in[4];  // (1024,1024)  fp32
    float* out = (float*)d_out;                  // (2,2048,1024) fp32

    // ws >= 22,806,528 B (proven in round 5)
    char* ws = (char*)d_ws;
    unsigned short* xb   = (unsigned short*)ws;               // 8,388,608
    unsigned short* Wqb  = (unsigned short*)(ws + 8388608);   // 2,359,296
    unsigned short* Wfb  = (unsigned short*)(ws + 10747904);  // 2,097,152
    unsigned short* qkvn = (unsigned short*)(ws + 12845056);  // 9,437,184
    unsigned short* vT   = (unsigned short*)(ws + 22282240);  //   524,288
    unsigned short* abuf = (unsigned short*)ws;               // alias xb (dead after gemm1)

    cvt_all<<<dim3(3136), 256, 0, stream>>>(x, Wqkv, Wfc, xb, Wqb, Wfb);
    gemm_mn<false><<<dim3(576), 512, 0, stream>>>(xb, Wqb, qkvn, 1024, 1152);
    ln_row<<<dim3(4096), 64, 0, stream>>>(qkvn, gamma, beta, vT);
    attn_kernel<<<dim3(16, 32), 512, 0, stream>>>(qkvn, vT, abuf);
    gemm_mn<true><<<dim3(512), 512, 0, stream>>>(abuf, Wfb, out, 1024, 1024);
}